// Round 1
// baseline (2466.263 us; speedup 1.0000x reference)
//
#include <hip/hip_runtime.h>
#include <hip/hip_bf16.h>

typedef __attribute__((ext_vector_type(8))) short short8;
typedef __attribute__((ext_vector_type(4))) float f32x4;
typedef __attribute__((ext_vector_type(4))) unsigned short u16x4;

#define DEVI static __device__ __forceinline__

constexpr int TT  = 1024;
constexpr int DD  = 768;
constexpr int FF  = 3072;
constexpr int VV  = 50257;
constexpr int VP  = 50304;   // padded vocab (multiple of 128)
constexpr int HH  = 12;
constexpr int BTOT = 2048;   // B*T

// ---------- helpers ----------
DEVI unsigned short f2bf(float f) {
    unsigned int u = __builtin_bit_cast(unsigned int, f);
    u += 0x7fffu + ((u >> 16) & 1u);
    return (unsigned short)(u >> 16);
}
DEVI float bf2f(unsigned short h) {
    unsigned int u = ((unsigned int)h) << 16;
    return __builtin_bit_cast(float, u);
}
DEVI f32x4 mfma16(short8 a, short8 b, f32x4 c) {
    return __builtin_amdgcn_mfma_f32_16x16x32_bf16(a, b, c, 0, 0, 0);
}

// ---------- weight conversion ----------
__global__ __launch_bounds__(256) void cvt4_k(const float* __restrict__ s,
                                              unsigned short* __restrict__ d, long n4) {
    long i = (long)blockIdx.x * 256 + threadIdx.x;
    if (i >= n4) return;
    float4 v = ((const float4*)s)[i];
    u16x4 o;
    o[0] = f2bf(v.x); o[1] = f2bf(v.y); o[2] = f2bf(v.z); o[3] = f2bf(v.w);
    ((u16x4*)d)[i] = o;
}

__global__ __launch_bounds__(192) void pad_tok_k(const float* __restrict__ s,
                                                 unsigned short* __restrict__ d) {
    int r = blockIdx.x;          // 0..VP-1
    int c = threadIdx.x * 4;     // 192*4 = 768
    u16x4 o = {0, 0, 0, 0};
    if (r < VV) {
        float4 v = *(const float4*)(s + (size_t)r * DD + c);
        o[0] = f2bf(v.x); o[1] = f2bf(v.y); o[2] = f2bf(v.z); o[3] = f2bf(v.w);
    }
    *(u16x4*)(d + (size_t)r * DD + c) = o;
}

// ---------- embedding ----------
__global__ __launch_bounds__(256) void embed_k(const int* __restrict__ idx,
                                               const float* __restrict__ tok,
                                               const float* __restrict__ pos,
                                               float* __restrict__ x) {
    int row = blockIdx.x;        // b*T + t
    int t = row & (TT - 1);
    int id = idx[row];
    for (int c = threadIdx.x; c < DD; c += 256)
        x[(size_t)row * DD + c] = tok[(size_t)id * DD + c] + pos[(size_t)t * DD + c];
}

// ---------- layernorm (row-per-block), f32 in -> bf16 out ----------
__global__ __launch_bounds__(256) void ln_k(const float* __restrict__ x,
                                            const float* __restrict__ w,
                                            const float* __restrict__ b,
                                            unsigned short* __restrict__ out) {
    int row = blockIdx.x;
    const float* xr = x + (size_t)row * DD;
    int tid = threadIdx.x;
    float v0 = xr[tid], v1 = xr[tid + 256], v2 = xr[tid + 512];
    float s = v0 + v1 + v2;
    #pragma unroll
    for (int m = 1; m < 64; m <<= 1) s += __shfl_xor(s, m);
    __shared__ float red[8];
    int wv = tid >> 6, ln = tid & 63;
    if (ln == 0) red[wv] = s;
    __syncthreads();
    float mean = (red[0] + red[1] + red[2] + red[3]) * (1.f / 768.f);
    float d0 = v0 - mean, d1 = v1 - mean, d2 = v2 - mean;
    float sq = d0 * d0 + d1 * d1 + d2 * d2;
    #pragma unroll
    for (int m = 1; m < 64; m <<= 1) sq += __shfl_xor(sq, m);
    if (ln == 0) red[4 + wv] = sq;
    __syncthreads();
    float var = (red[4] + red[5] + red[6] + red[7]) * (1.f / 768.f);
    float rstd = rsqrtf(var + 1e-5f);
    out[(size_t)row * DD + tid]       = f2bf(d0 * rstd * w[tid]       + b[tid]);
    out[(size_t)row * DD + tid + 256] = f2bf(d1 * rstd * w[tid + 256] + b[tid + 256]);
    out[(size_t)row * DD + tid + 512] = f2bf(d2 * rstd * w[tid + 512] + b[tid + 512]);
}

// ---------- GEMM: C[M,N] = A[M,K](bf16) @ B[N,K]^T(bf16)  (m97 structure) ----------
// EPI 0: bf16 out, +bias.  1: bf16 out, +bias, exact GELU.
// EPI 2: f32 residual accumulate (Cf += acc + bias).  3: f32 out, col-guarded, no bias.
template<int EPI>
__global__ __launch_bounds__(256) void gemm_bt(const unsigned short* __restrict__ A,
                                               const unsigned short* __restrict__ B,
                                               const float* __restrict__ bias,
                                               float* __restrict__ Cf,
                                               unsigned short* __restrict__ Cb,
                                               int M, int N, int K, int ldc, int Nreal) {
    __shared__ __align__(16) unsigned short As[128 * 32];
    __shared__ __align__(16) unsigned short Bs[128 * 32];
    const int tid = threadIdx.x;
    const int wave = tid >> 6, lane = tid & 63;
    const int m0 = blockIdx.y * 128, n0 = blockIdx.x * 128;
    const int wm = wave >> 1, wn = wave & 1;
    const int g = lane >> 4, r16 = lane & 15;

    f32x4 acc[4][4] = {};

    const int srow = wave * 32 + (lane >> 2);   // staging row (i adds +16)
    const int scol = (lane & 3) * 8;
    const unsigned short* Aptr = A + (size_t)(m0 + srow) * K + scol;
    const unsigned short* Bptr = B + (size_t)(n0 + srow) * K + scol;

    const int nsteps = K >> 5;
    for (int kt = 0; kt < nsteps; ++kt) {
        const int k0 = kt << 5;
        #pragma unroll
        for (int i = 0; i < 2; i++) {
            __builtin_amdgcn_global_load_lds(
                (const __attribute__((address_space(1))) void*)(Aptr + (size_t)i * 16 * K + k0),
                (__attribute__((address_space(3))) void*)(As + (wave * 2 + i) * 512),
                16, 0, 0);
        }
        #pragma unroll
        for (int i = 0; i < 2; i++) {
            __builtin_amdgcn_global_load_lds(
                (const __attribute__((address_space(1))) void*)(Bptr + (size_t)i * 16 * K + k0),
                (__attribute__((address_space(3))) void*)(Bs + (wave * 2 + i) * 512),
                16, 0, 0);
        }
        asm volatile("s_waitcnt vmcnt(0)" ::: "memory");
        __syncthreads();
        short8 af[4], bfr[4];
        #pragma unroll
        for (int m = 0; m < 4; m++)
            af[m] = *(const short8*)&As[(wm * 64 + m * 16 + r16) * 32 + g * 8];
        #pragma unroll
        for (int n = 0; n < 4; n++)
            bfr[n] = *(const short8*)&Bs[(wn * 64 + n * 16 + r16) * 32 + g * 8];
        #pragma unroll
        for (int m = 0; m < 4; m++)
            #pragma unroll
            for (int n = 0; n < 4; n++)
                acc[m][n] = mfma16(af[m], bfr[n], acc[m][n]);
        __syncthreads();
    }

    #pragma unroll
    for (int n = 0; n < 4; n++) {
        int gcol = n0 + wn * 64 + n * 16 + r16;
        float bv = (EPI == 3) ? 0.f : bias[gcol];
        #pragma unroll
        for (int m = 0; m < 4; m++) {
            int grow0 = m0 + wm * 64 + m * 16 + g * 4;
            #pragma unroll
            for (int r = 0; r < 4; r++) {
                float v = acc[m][n][r] + bv;
                size_t off = (size_t)(grow0 + r) * ldc + gcol;
                if (EPI == 0) {
                    Cb[off] = f2bf(v);
                } else if (EPI == 1) {
                    float ge = 0.5f * v * (1.f + erff(v * 0.70710678118654752f));
                    Cb[off] = f2bf(ge);
                } else if (EPI == 2) {
                    Cf[off] = Cf[off] + v;
                } else {
                    if (gcol < Nreal) Cf[off] = v;
                }
            }
        }
    }
}

// ---------- V transpose: qkv[b,t, 2D + h*64 + d] -> vT[(bh*64+d)*T + t] ----------
__global__ __launch_bounds__(256) void vtrans_k(const unsigned short* __restrict__ qkv,
                                                unsigned short* __restrict__ vT) {
    int bh = blockIdx.y;
    int b = bh / HH, h = bh - b * HH;
    int t0 = blockIdx.x * 64;
    __shared__ unsigned short tile[64][65];
    int tid = threadIdx.x;
    int dl = tid & 63, tq = tid >> 6;
    #pragma unroll
    for (int i = 0; i < 16; i++) {
        int tl = i * 4 + tq;
        tile[tl][dl] = qkv[(size_t)(b * TT + t0 + tl) * (3 * DD) + 2 * DD + h * 64 + dl];
    }
    __syncthreads();
    #pragma unroll
    for (int i = 0; i < 16; i++) {
        int d2 = i * 4 + tq;
        vT[((size_t)bh * 64 + d2) * TT + t0 + dl] = tile[dl][d2];
    }
}

// ---------- causal flash attention ----------
__global__ __launch_bounds__(256) void attn_k(const unsigned short* __restrict__ qkv,
                                              const unsigned short* __restrict__ vT,
                                              unsigned short* __restrict__ out) {
    const int w = threadIdx.x >> 6, lane = threadIdx.x & 63;
    const int g = lane >> 4, r16 = lane & 15;
    const int qt = blockIdx.x, bh = blockIdx.y;
    const int b = bh / HH, h = bh - b * HH;
    __shared__ __align__(16) unsigned short Plds[4 * 1280];  // 4 waves x 16 rows x 80 (stride)
    const int qbase = qt * 64 + w * 16;

    short8 aq[2];
    #pragma unroll
    for (int kk = 0; kk < 2; kk++)
        aq[kk] = *(const short8*)(qkv + (size_t)(b * TT + qbase + r16) * (3 * DD)
                                  + h * 64 + kk * 32 + g * 8);

    f32x4 oacc[4] = {};
    float mrow[4], lrow[4];
    #pragma unroll
    for (int r = 0; r < 4; r++) { mrow[r] = -1e30f; lrow[r] = 0.f; }

    for (int kt = 0; kt <= qt; ++kt) {
        f32x4 sacc[4] = {};
        #pragma unroll
        for (int j = 0; j < 4; j++) {
            #pragma unroll
            for (int kk = 0; kk < 2; kk++) {
                short8 bk = *(const short8*)(qkv + (size_t)(b * TT + kt * 64 + j * 16 + r16) * (3 * DD)
                                             + DD + h * 64 + kk * 32 + g * 8);
                sacc[j] = mfma16(aq[kk], bk, sacc[j]);
            }
        }
        const bool diag = (kt == qt);
        float s[4][4], pm[4];
        #pragma unroll
        for (int r = 0; r < 4; r++) pm[r] = -1e30f;
        #pragma unroll
        for (int j = 0; j < 4; j++) {
            int kcol = kt * 64 + j * 16 + r16;
            #pragma unroll
            for (int r = 0; r < 4; r++) {
                float v = sacc[j][r] * 0.125f;
                if (diag && kcol > qbase + g * 4 + r) v = -1e30f;
                s[j][r] = v;
                pm[r] = fmaxf(pm[r], v);
            }
        }
        #pragma unroll
        for (int r = 0; r < 4; r++) {
            #pragma unroll
            for (int msk = 1; msk < 16; msk <<= 1)
                pm[r] = fmaxf(pm[r], __shfl_xor(pm[r], msk));
        }
        float cf[4], rs[4];
        #pragma unroll
        for (int r = 0; r < 4; r++) {
            float mn = fmaxf(mrow[r], pm[r]);
            cf[r] = __expf(mrow[r] - mn);
            mrow[r] = mn;
            rs[r] = 0.f;
        }
        #pragma unroll
        for (int j = 0; j < 4; j++)
            #pragma unroll
            for (int r = 0; r < 4; r++) {
                float p = __expf(s[j][r] - mrow[r]);
                s[j][r] = p;
                rs[r] += p;
            }
        #pragma unroll
        for (int r = 0; r < 4; r++) {
            #pragma unroll
            for (int msk = 1; msk < 16; msk <<= 1) rs[r] += __shfl_xor(rs[r], msk);
            lrow[r] = lrow[r] * cf[r] + rs[r];
        }
        #pragma unroll
        for (int jd = 0; jd < 4; jd++)
            #pragma unroll
            for (int r = 0; r < 4; r++) oacc[jd][r] *= cf[r];

        asm volatile("s_waitcnt lgkmcnt(0)" ::: "memory");
        #pragma unroll
        for (int j = 0; j < 4; j++)
            #pragma unroll
            for (int r = 0; r < 4; r++)
                Plds[w * 1280 + (g * 4 + r) * 80 + j * 16 + r16] = f2bf(s[j][r]);
        asm volatile("s_waitcnt lgkmcnt(0)" ::: "memory");
        short8 ap[2];
        #pragma unroll
        for (int kk = 0; kk < 2; kk++)
            ap[kk] = *(const short8*)&Plds[w * 1280 + r16 * 80 + kk * 32 + g * 8];
        #pragma unroll
        for (int jd = 0; jd < 4; jd++) {
            #pragma unroll
            for (int kk = 0; kk < 2; kk++) {
                short8 bv = *(const short8*)(vT + ((size_t)bh * 64 + jd * 16 + r16) * TT
                                             + kt * 64 + kk * 32 + g * 8);
                oacc[jd] = mfma16(ap[kk], bv, oacc[jd]);
            }
        }
    }
    #pragma unroll
    for (int jd = 0; jd < 4; jd++) {
        int d = h * 64 + jd * 16 + r16;
        #pragma unroll
        for (int r = 0; r < 4; r++) {
            int t = qbase + g * 4 + r;
            out[(size_t)(b * TT + t) * DD + d] = f2bf(oacc[jd][r] / lrow[r]);
        }
    }
}

// ---------- workspace layout (bytes) ----------
#define OFF_X    0u
#define OFF_H    (6291456u)
#define OFF_QKV  (OFF_H   + 3145728u)
#define OFF_VT   (OFF_QKV + 9437184u)
#define OFF_ATT  (OFF_VT  + 3145728u)
#define OFF_GEL  (OFF_ATT + 3145728u)
#define OFF_WQ   (OFF_GEL + 12582912u)
#define OFF_WO   (OFF_WQ  + 21233664u)
#define OFF_WF1  (OFF_WO  + 7077888u)
#define OFF_WF2  (OFF_WF1 + 28311552u)
#define OFF_TOK  (OFF_WF2 + 28311552u)

extern "C" void kernel_launch(void* const* d_in, const int* in_sizes, int n_in,
                              void* d_out, int out_size, void* d_ws, size_t ws_size,
                              hipStream_t stream) {
    const int*   idx  = (const int*)  d_in[0];
    const float* tok  = (const float*)d_in[1];
    const float* pos  = (const float*)d_in[2];
    const float* ln1w = (const float*)d_in[3];
    const float* ln1b = (const float*)d_in[4];
    const float* qkvw = (const float*)d_in[5];
    const float* qkvb = (const float*)d_in[6];
    const float* outw = (const float*)d_in[7];
    const float* outb = (const float*)d_in[8];
    const float* ln2w = (const float*)d_in[9];
    const float* ln2b = (const float*)d_in[10];
    const float* fc1w = (const float*)d_in[11];
    const float* fc1b = (const float*)d_in[12];
    const float* fc2w = (const float*)d_in[13];
    const float* fc2b = (const float*)d_in[14];
    const float* lnfw = (const float*)d_in[15];
    const float* lnfb = (const float*)d_in[16];

    char* ws = (char*)d_ws;
    float*          x    = (float*)         (ws + OFF_X);
    unsigned short* hbuf = (unsigned short*)(ws + OFF_H);
    unsigned short* qkvB = (unsigned short*)(ws + OFF_QKV);
    unsigned short* vT   = (unsigned short*)(ws + OFF_VT);
    unsigned short* attB = (unsigned short*)(ws + OFF_ATT);
    unsigned short* gelB = (unsigned short*)(ws + OFF_GEL);
    unsigned short* wq   = (unsigned short*)(ws + OFF_WQ);
    unsigned short* wo   = (unsigned short*)(ws + OFF_WO);
    unsigned short* wf1  = (unsigned short*)(ws + OFF_WF1);
    unsigned short* wf2  = (unsigned short*)(ws + OFF_WF2);
    unsigned short* tokp = (unsigned short*)(ws + OFF_TOK);

    // weight conversions (f32 -> bf16)
    cvt4_k<<<10368, 256, 0, stream>>>(qkvw, wq,  (long)6 * 2304 * 768 / 4);
    cvt4_k<<<3456,  256, 0, stream>>>(outw, wo,  (long)6 * 768  * 768 / 4);
    cvt4_k<<<13824, 256, 0, stream>>>(fc1w, wf1, (long)6 * 3072 * 768 / 4);
    cvt4_k<<<13824, 256, 0, stream>>>(fc2w, wf2, (long)6 * 768  * 3072 / 4);
    pad_tok_k<<<VP, 192, 0, stream>>>(tok, tokp);

    embed_k<<<BTOT, 256, 0, stream>>>(idx, tok, pos, x);

    for (int l = 0; l < 6; l++) {
        ln_k<<<BTOT, 256, 0, stream>>>(x, ln1w + l * DD, ln1b + l * DD, hbuf);
        gemm_bt<0><<<dim3(18, 16), 256, 0, stream>>>(hbuf, wq + (size_t)l * 2304 * 768,
                                                     qkvb + l * 2304, nullptr, qkvB,
                                                     BTOT, 2304, 768, 2304, 2304);
        vtrans_k<<<dim3(16, 24), 256, 0, stream>>>(qkvB, vT);
        attn_k<<<dim3(16, 24), 256, 0, stream>>>(qkvB, vT, attB);
        gemm_bt<2><<<dim3(6, 16), 256, 0, stream>>>(attB, wo + (size_t)l * 768 * 768,
                                                    outb + l * DD, x, nullptr,
                                                    BTOT, 768, 768, 768, 768);
        ln_k<<<BTOT, 256, 0, stream>>>(x, ln2w + l * DD, ln2b + l * DD, hbuf);
        gemm_bt<1><<<dim3(24, 16), 256, 0, stream>>>(hbuf, wf1 + (size_t)l * 3072 * 768,
                                                     fc1b + l * FF, nullptr, gelB,
                                                     BTOT, 3072, 768, 3072, 3072);
        gemm_bt<2><<<dim3(6, 16), 256, 0, stream>>>(gelB, wf2 + (size_t)l * 768 * 3072,
                                                    fc2b + l * DD, x, nullptr,
                                                    BTOT, 768, 3072, 768, 768);
    }
    ln_k<<<BTOT, 256, 0, stream>>>(x, lnfw, lnfb, hbuf);
    gemm_bt<3><<<dim3(VP / 128, 16), 256, 0, stream>>>(hbuf, tokp, nullptr,
                                                       (float*)d_out, nullptr,
                                                       BTOT, VP, 768, VV, VV);
}

// Round 2
// 2170.287 us; speedup vs baseline: 1.1364x; 1.1364x over previous
//
#include <hip/hip_runtime.h>
#include <hip/hip_bf16.h>

typedef __attribute__((ext_vector_type(8))) short short8;
typedef __attribute__((ext_vector_type(4))) float f32x4;
typedef __attribute__((ext_vector_type(4))) unsigned short u16x4;

#define DEVI static __device__ __forceinline__

constexpr int TT  = 1024;
constexpr int DD  = 768;
constexpr int FF  = 3072;
constexpr int VV  = 50257;
constexpr int VP2 = 51200;   // padded vocab: 400 panels of 128 = 50 panels per XCD
constexpr int HH  = 12;
constexpr int BTOT = 2048;   // B*T

// ---------- helpers ----------
DEVI unsigned short f2bf(float f) {
    unsigned int u = __builtin_bit_cast(unsigned int, f);
    u += 0x7fffu + ((u >> 16) & 1u);
    return (unsigned short)(u >> 16);
}
DEVI float bf2f(unsigned short h) {
    unsigned int u = ((unsigned int)h) << 16;
    return __builtin_bit_cast(float, u);
}
DEVI f32x4 mfma16(short8 a, short8 b, f32x4 c) {
    return __builtin_amdgcn_mfma_f32_16x16x32_bf16(a, b, c, 0, 0, 0);
}

// ---------- weight conversion ----------
__global__ __launch_bounds__(256) void cvt4_k(const float* __restrict__ s,
                                              unsigned short* __restrict__ d, long n4) {
    long i = (long)blockIdx.x * 256 + threadIdx.x;
    if (i >= n4) return;
    float4 v = ((const float4*)s)[i];
    u16x4 o;
    o[0] = f2bf(v.x); o[1] = f2bf(v.y); o[2] = f2bf(v.z); o[3] = f2bf(v.w);
    ((u16x4*)d)[i] = o;
}

__global__ __launch_bounds__(192) void pad_tok_k(const float* __restrict__ s,
                                                 unsigned short* __restrict__ d) {
    int r = blockIdx.x;          // 0..VP2-1
    int c = threadIdx.x * 4;     // 192*4 = 768
    u16x4 o = {0, 0, 0, 0};
    if (r < VV) {
        float4 v = *(const float4*)(s + (size_t)r * DD + c);
        o[0] = f2bf(v.x); o[1] = f2bf(v.y); o[2] = f2bf(v.z); o[3] = f2bf(v.w);
    }
    *(u16x4*)(d + (size_t)r * DD + c) = o;
}

// ---------- embedding ----------
__global__ __launch_bounds__(256) void embed_k(const int* __restrict__ idx,
                                               const float* __restrict__ tok,
                                               const float* __restrict__ pos,
                                               float* __restrict__ x) {
    int row = blockIdx.x;        // b*T + t
    int t = row & (TT - 1);
    int id = idx[row];
    for (int c = threadIdx.x; c < DD; c += 256)
        x[(size_t)row * DD + c] = tok[(size_t)id * DD + c] + pos[(size_t)t * DD + c];
}

// ---------- layernorm (row-per-block), f32 in -> bf16 out ----------
__global__ __launch_bounds__(256) void ln_k(const float* __restrict__ x,
                                            const float* __restrict__ w,
                                            const float* __restrict__ b,
                                            unsigned short* __restrict__ out) {
    int row = blockIdx.x;
    const float* xr = x + (size_t)row * DD;
    int tid = threadIdx.x;
    float v0 = xr[tid], v1 = xr[tid + 256], v2 = xr[tid + 512];
    float s = v0 + v1 + v2;
    #pragma unroll
    for (int m = 1; m < 64; m <<= 1) s += __shfl_xor(s, m);
    __shared__ float red[8];
    int wv = tid >> 6, ln = tid & 63;
    if (ln == 0) red[wv] = s;
    __syncthreads();
    float mean = (red[0] + red[1] + red[2] + red[3]) * (1.f / 768.f);
    float d0 = v0 - mean, d1 = v1 - mean, d2 = v2 - mean;
    float sq = d0 * d0 + d1 * d1 + d2 * d2;
    #pragma unroll
    for (int m = 1; m < 64; m <<= 1) sq += __shfl_xor(sq, m);
    if (ln == 0) red[4 + wv] = sq;
    __syncthreads();
    float var = (red[4] + red[5] + red[6] + red[7]) * (1.f / 768.f);
    float rstd = rsqrtf(var + 1e-5f);
    out[(size_t)row * DD + tid]       = f2bf(d0 * rstd * w[tid]       + b[tid]);
    out[(size_t)row * DD + tid + 256] = f2bf(d1 * rstd * w[tid + 256] + b[tid + 256]);
    out[(size_t)row * DD + tid + 512] = f2bf(d2 * rstd * w[tid + 512] + b[tid + 512]);
}

// ---------- GEMM: C[M,N] = A[M,K](bf16) @ B[N,K]^T(bf16)  (m97 structure) ----------
// EPI 0: bf16 out, +bias.  1: bf16 out, +bias, exact GELU.
// EPI 2: f32 residual accumulate (Cf += acc + bias).  3: f32 out, col-guarded, no bias.
// XSW: 1D grid, XCD-slab mapping (each XCD owns a contiguous N-slab, M-fastest inside).
template<int EPI, bool XSW>
__global__ __launch_bounds__(256) void gemm_bt(const unsigned short* __restrict__ A,
                                               const unsigned short* __restrict__ B,
                                               const float* __restrict__ bias,
                                               float* __restrict__ Cf,
                                               unsigned short* __restrict__ Cb,
                                               int M, int N, int K, int ldc, int Nreal) {
    __shared__ __align__(16) unsigned short As[128 * 32];
    __shared__ __align__(16) unsigned short Bs[128 * 32];
    const int tid = threadIdx.x;
    const int wave = tid >> 6, lane = tid & 63;
    int m0, n0;
    if (XSW) {
        // grid = (M/128)*(N/128) 1D; N/128 must be divisible by 8, M/128 == 16.
        int lid = blockIdx.x;
        int xcd = lid & 7;
        int per = lid >> 3;                 // 0 .. (total/8)-1
        int mb  = per & 15;                 // M-fastest
        int nper = N >> 10;                 // (N/128)/8 panels per XCD
        int nb  = xcd * nper + (per >> 4);
        m0 = mb << 7; n0 = nb << 7;
    } else {
        m0 = blockIdx.y * 128; n0 = blockIdx.x * 128;
    }
    const int wm = wave >> 1, wn = wave & 1;
    const int g = lane >> 4, r16 = lane & 15;

    f32x4 acc[4][4] = {};

    const int srow = wave * 32 + (lane >> 2);   // staging row (i adds +16)
    const int scol = (lane & 3) * 8;
    const unsigned short* Aptr = A + (size_t)(m0 + srow) * K + scol;
    const unsigned short* Bptr = B + (size_t)(n0 + srow) * K + scol;

    const int nsteps = K >> 5;
    for (int kt = 0; kt < nsteps; ++kt) {
        const int k0 = kt << 5;
        #pragma unroll
        for (int i = 0; i < 2; i++) {
            __builtin_amdgcn_global_load_lds(
                (const __attribute__((address_space(1))) void*)(Aptr + (size_t)i * 16 * K + k0),
                (__attribute__((address_space(3))) void*)(As + (wave * 2 + i) * 512),
                16, 0, 0);
        }
        #pragma unroll
        for (int i = 0; i < 2; i++) {
            __builtin_amdgcn_global_load_lds(
                (const __attribute__((address_space(1))) void*)(Bptr + (size_t)i * 16 * K + k0),
                (__attribute__((address_space(3))) void*)(Bs + (wave * 2 + i) * 512),
                16, 0, 0);
        }
        asm volatile("s_waitcnt vmcnt(0)" ::: "memory");
        __syncthreads();
        short8 af[4], bfr[4];
        #pragma unroll
        for (int m = 0; m < 4; m++)
            af[m] = *(const short8*)&As[(wm * 64 + m * 16 + r16) * 32 + g * 8];
        #pragma unroll
        for (int n = 0; n < 4; n++)
            bfr[n] = *(const short8*)&Bs[(wn * 64 + n * 16 + r16) * 32 + g * 8];
        #pragma unroll
        for (int m = 0; m < 4; m++)
            #pragma unroll
            for (int n = 0; n < 4; n++)
                acc[m][n] = mfma16(af[m], bfr[n], acc[m][n]);
        __syncthreads();
    }

    #pragma unroll
    for (int n = 0; n < 4; n++) {
        int gcol = n0 + wn * 64 + n * 16 + r16;
        float bv = (EPI == 3) ? 0.f : bias[gcol];
        #pragma unroll
        for (int m = 0; m < 4; m++) {
            int grow0 = m0 + wm * 64 + m * 16 + g * 4;
            #pragma unroll
            for (int r = 0; r < 4; r++) {
                float v = acc[m][n][r] + bv;
                size_t off = (size_t)(grow0 + r) * ldc + gcol;
                if (EPI == 0) {
                    Cb[off] = f2bf(v);
                } else if (EPI == 1) {
                    float ge = 0.5f * v * (1.f + erff(v * 0.70710678118654752f));
                    Cb[off] = f2bf(ge);
                } else if (EPI == 2) {
                    Cf[off] = Cf[off] + v;
                } else {
                    if (gcol < Nreal) Cf[off] = v;
                }
            }
        }
    }
}

// ---------- 64x64-tile GEMM (for small-N GEMMs: out-proj, fc2), residual accumulate ----------
__global__ __launch_bounds__(256) void gemm64_bt(const unsigned short* __restrict__ A,
                                                 const unsigned short* __restrict__ B,
                                                 const float* __restrict__ bias,
                                                 float* __restrict__ Cf,
                                                 int M, int N, int K, int ldc) {
    __shared__ __align__(16) unsigned short As[64 * 32];
    __shared__ __align__(16) unsigned short Bs[64 * 32];
    const int tid = threadIdx.x;
    const int wave = tid >> 6, lane = tid & 63;
    const int m0 = blockIdx.y * 64, n0 = blockIdx.x * 64;
    const int wm = wave >> 1, wn = wave & 1;
    const int g = lane >> 4, r16 = lane & 15;

    f32x4 acc[2][2] = {};

    const int srow = wave * 16 + (lane >> 2);
    const int scol = (lane & 3) * 8;
    const unsigned short* Aptr = A + (size_t)(m0 + srow) * K + scol;
    const unsigned short* Bptr = B + (size_t)(n0 + srow) * K + scol;

    const int nsteps = K >> 5;
    for (int kt = 0; kt < nsteps; ++kt) {
        const int k0 = kt << 5;
        __builtin_amdgcn_global_load_lds(
            (const __attribute__((address_space(1))) void*)(Aptr + k0),
            (__attribute__((address_space(3))) void*)(As + wave * 512),
            16, 0, 0);
        __builtin_amdgcn_global_load_lds(
            (const __attribute__((address_space(1))) void*)(Bptr + k0),
            (__attribute__((address_space(3))) void*)(Bs + wave * 512),
            16, 0, 0);
        asm volatile("s_waitcnt vmcnt(0)" ::: "memory");
        __syncthreads();
        short8 af[2], bfr[2];
        #pragma unroll
        for (int m = 0; m < 2; m++)
            af[m] = *(const short8*)&As[(wm * 32 + m * 16 + r16) * 32 + g * 8];
        #pragma unroll
        for (int n = 0; n < 2; n++)
            bfr[n] = *(const short8*)&Bs[(wn * 32 + n * 16 + r16) * 32 + g * 8];
        #pragma unroll
        for (int m = 0; m < 2; m++)
            #pragma unroll
            for (int n = 0; n < 2; n++)
                acc[m][n] = mfma16(af[m], bfr[n], acc[m][n]);
        __syncthreads();
    }

    #pragma unroll
    for (int n = 0; n < 2; n++) {
        int gcol = n0 + wn * 32 + n * 16 + r16;
        float bv = bias[gcol];
        #pragma unroll
        for (int m = 0; m < 2; m++) {
            int grow0 = m0 + wm * 32 + m * 16 + g * 4;
            #pragma unroll
            for (int r = 0; r < 4; r++) {
                size_t off = (size_t)(grow0 + r) * ldc + gcol;
                Cf[off] = Cf[off] + acc[m][n][r] + bv;
            }
        }
    }
}

// ---------- V transpose: qkv[b,t, 2D + h*64 + d] -> vT[(bh*64+d)*T + t] ----------
__global__ __launch_bounds__(256) void vtrans_k(const unsigned short* __restrict__ qkv,
                                                unsigned short* __restrict__ vT) {
    int bh = blockIdx.y;
    int b = bh / HH, h = bh - b * HH;
    int t0 = blockIdx.x * 64;
    __shared__ unsigned short tile[64][65];
    int tid = threadIdx.x;
    int dl = tid & 63, tq = tid >> 6;
    #pragma unroll
    for (int i = 0; i < 16; i++) {
        int tl = i * 4 + tq;
        tile[tl][dl] = qkv[(size_t)(b * TT + t0 + tl) * (3 * DD) + 2 * DD + h * 64 + dl];
    }
    __syncthreads();
    #pragma unroll
    for (int i = 0; i < 16; i++) {
        int d2 = i * 4 + tq;
        vT[((size_t)bh * 64 + d2) * TT + t0 + dl] = tile[dl][d2];
    }
}

// ---------- causal flash attention ----------
__global__ __launch_bounds__(256) void attn_k(const unsigned short* __restrict__ qkv,
                                              const unsigned short* __restrict__ vT,
                                              unsigned short* __restrict__ out) {
    const int w = threadIdx.x >> 6, lane = threadIdx.x & 63;
    const int g = lane >> 4, r16 = lane & 15;
    const int qt = blockIdx.x, bh = blockIdx.y;
    const int b = bh / HH, h = bh - b * HH;
    __shared__ __align__(16) unsigned short Plds[4 * 1280];  // 4 waves x 16 rows x 80 (stride)
    const int qbase = qt * 64 + w * 16;

    short8 aq[2];
    #pragma unroll
    for (int kk = 0; kk < 2; kk++)
        aq[kk] = *(const short8*)(qkv + (size_t)(b * TT + qbase + r16) * (3 * DD)
                                  + h * 64 + kk * 32 + g * 8);

    f32x4 oacc[4] = {};
    float mrow[4], lrow[4];
    #pragma unroll
    for (int r = 0; r < 4; r++) { mrow[r] = -1e30f; lrow[r] = 0.f; }

    for (int kt = 0; kt <= qt; ++kt) {
        f32x4 sacc[4] = {};
        #pragma unroll
        for (int j = 0; j < 4; j++) {
            #pragma unroll
            for (int kk = 0; kk < 2; kk++) {
                short8 bk = *(const short8*)(qkv + (size_t)(b * TT + kt * 64 + j * 16 + r16) * (3 * DD)
                                             + DD + h * 64 + kk * 32 + g * 8);
                sacc[j] = mfma16(aq[kk], bk, sacc[j]);
            }
        }
        const bool diag = (kt == qt);
        float s[4][4], pm[4];
        #pragma unroll
        for (int r = 0; r < 4; r++) pm[r] = -1e30f;
        #pragma unroll
        for (int j = 0; j < 4; j++) {
            int kcol = kt * 64 + j * 16 + r16;
            #pragma unroll
            for (int r = 0; r < 4; r++) {
                float v = sacc[j][r] * 0.125f;
                if (diag && kcol > qbase + g * 4 + r) v = -1e30f;
                s[j][r] = v;
                pm[r] = fmaxf(pm[r], v);
            }
        }
        #pragma unroll
        for (int r = 0; r < 4; r++) {
            #pragma unroll
            for (int msk = 1; msk < 16; msk <<= 1)
                pm[r] = fmaxf(pm[r], __shfl_xor(pm[r], msk));
        }
        float cf[4], rs[4];
        #pragma unroll
        for (int r = 0; r < 4; r++) {
            float mn = fmaxf(mrow[r], pm[r]);
            cf[r] = __expf(mrow[r] - mn);
            mrow[r] = mn;
            rs[r] = 0.f;
        }
        #pragma unroll
        for (int j = 0; j < 4; j++)
            #pragma unroll
            for (int r = 0; r < 4; r++) {
                float p = __expf(s[j][r] - mrow[r]);
                s[j][r] = p;
                rs[r] += p;
            }
        #pragma unroll
        for (int r = 0; r < 4; r++) {
            #pragma unroll
            for (int msk = 1; msk < 16; msk <<= 1) rs[r] += __shfl_xor(rs[r], msk);
            lrow[r] = lrow[r] * cf[r] + rs[r];
        }
        #pragma unroll
        for (int jd = 0; jd < 4; jd++)
            #pragma unroll
            for (int r = 0; r < 4; r++) oacc[jd][r] *= cf[r];

        asm volatile("s_waitcnt lgkmcnt(0)" ::: "memory");
        #pragma unroll
        for (int j = 0; j < 4; j++)
            #pragma unroll
            for (int r = 0; r < 4; r++)
                Plds[w * 1280 + (g * 4 + r) * 80 + j * 16 + r16] = f2bf(s[j][r]);
        asm volatile("s_waitcnt lgkmcnt(0)" ::: "memory");
        short8 ap[2];
        #pragma unroll
        for (int kk = 0; kk < 2; kk++)
            ap[kk] = *(const short8*)&Plds[w * 1280 + r16 * 80 + kk * 32 + g * 8];
        #pragma unroll
        for (int jd = 0; jd < 4; jd++) {
            #pragma unroll
            for (int kk = 0; kk < 2; kk++) {
                short8 bv = *(const short8*)(vT + ((size_t)bh * 64 + jd * 16 + r16) * TT
                                             + kt * 64 + kk * 32 + g * 8);
                oacc[jd] = mfma16(ap[kk], bv, oacc[jd]);
            }
        }
    }
    #pragma unroll
    for (int jd = 0; jd < 4; jd++) {
        int d = h * 64 + jd * 16 + r16;
        #pragma unroll
        for (int r = 0; r < 4; r++) {
            int t = qbase + g * 4 + r;
            out[(size_t)(b * TT + t) * DD + d] = f2bf(oacc[jd][r] / lrow[r]);
        }
    }
}

// ---------- workspace layout (bytes) ----------
#define OFF_X    0u
#define OFF_H    (6291456u)
#define OFF_QKV  (OFF_H   + 3145728u)
#define OFF_VT   (OFF_QKV + 9437184u)
#define OFF_ATT  (OFF_VT  + 3145728u)
#define OFF_GEL  (OFF_ATT + 3145728u)
#define OFF_WQ   (OFF_GEL + 12582912u)
#define OFF_WO   (OFF_WQ  + 21233664u)
#define OFF_WF1  (OFF_WO  + 7077888u)
#define OFF_WF2  (OFF_WF1 + 28311552u)
#define OFF_TOK  (OFF_WF2 + 28311552u)

extern "C" void kernel_launch(void* const* d_in, const int* in_sizes, int n_in,
                              void* d_out, int out_size, void* d_ws, size_t ws_size,
                              hipStream_t stream) {
    const int*   idx  = (const int*)  d_in[0];
    const float* tok  = (const float*)d_in[1];
    const float* pos  = (const float*)d_in[2];
    const float* ln1w = (const float*)d_in[3];
    const float* ln1b = (const float*)d_in[4];
    const float* qkvw = (const float*)d_in[5];
    const float* qkvb = (const float*)d_in[6];
    const float* outw = (const float*)d_in[7];
    const float* outb = (const float*)d_in[8];
    const float* ln2w = (const float*)d_in[9];
    const float* ln2b = (const float*)d_in[10];
    const float* fc1w = (const float*)d_in[11];
    const float* fc1b = (const float*)d_in[12];
    const float* fc2w = (const float*)d_in[13];
    const float* fc2b = (const float*)d_in[14];
    const float* lnfw = (const float*)d_in[15];
    const float* lnfb = (const float*)d_in[16];

    char* ws = (char*)d_ws;
    float*          x    = (float*)         (ws + OFF_X);
    unsigned short* hbuf = (unsigned short*)(ws + OFF_H);
    unsigned short* qkvB = (unsigned short*)(ws + OFF_QKV);
    unsigned short* vT   = (unsigned short*)(ws + OFF_VT);
    unsigned short* attB = (unsigned short*)(ws + OFF_ATT);
    unsigned short* gelB = (unsigned short*)(ws + OFF_GEL);
    unsigned short* wq   = (unsigned short*)(ws + OFF_WQ);
    unsigned short* wo   = (unsigned short*)(ws + OFF_WO);
    unsigned short* wf1  = (unsigned short*)(ws + OFF_WF1);
    unsigned short* wf2  = (unsigned short*)(ws + OFF_WF2);
    unsigned short* tokp = (unsigned short*)(ws + OFF_TOK);

    // weight conversions (f32 -> bf16)
    cvt4_k<<<10368, 256, 0, stream>>>(qkvw, wq,  (long)6 * 2304 * 768 / 4);
    cvt4_k<<<3456,  256, 0, stream>>>(outw, wo,  (long)6 * 768  * 768 / 4);
    cvt4_k<<<13824, 256, 0, stream>>>(fc1w, wf1, (long)6 * 3072 * 768 / 4);
    cvt4_k<<<13824, 256, 0, stream>>>(fc2w, wf2, (long)6 * 768  * 3072 / 4);
    pad_tok_k<<<VP2, 192, 0, stream>>>(tok, tokp);

    embed_k<<<BTOT, 256, 0, stream>>>(idx, tok, pos, x);

    for (int l = 0; l < 6; l++) {
        ln_k<<<BTOT, 256, 0, stream>>>(x, ln1w + l * DD, ln1b + l * DD, hbuf);
        gemm_bt<0, false><<<dim3(18, 16), 256, 0, stream>>>(hbuf, wq + (size_t)l * 2304 * 768,
                                                     qkvb + l * 2304, nullptr, qkvB,
                                                     BTOT, 2304, 768, 2304, 2304);
        vtrans_k<<<dim3(16, 24), 256, 0, stream>>>(qkvB, vT);
        attn_k<<<dim3(16, 24), 256, 0, stream>>>(qkvB, vT, attB);
        gemm64_bt<<<dim3(12, 32), 256, 0, stream>>>(attB, wo + (size_t)l * 768 * 768,
                                                    outb + l * DD, x,
                                                    BTOT, 768, 768, 768);
        ln_k<<<BTOT, 256, 0, stream>>>(x, ln2w + l * DD, ln2b + l * DD, hbuf);
        gemm_bt<1, false><<<dim3(24, 16), 256, 0, stream>>>(hbuf, wf1 + (size_t)l * 3072 * 768,
                                                     fc1b + l * FF, nullptr, gelB,
                                                     BTOT, 3072, 768, 3072, 3072);
        gemm64_bt<<<dim3(12, 32), 256, 0, stream>>>(gelB, wf2 + (size_t)l * 768 * 3072,
                                                    fc2b + l * DD, x,
                                                    BTOT, 768, 3072, 768);
    }
    ln_k<<<BTOT, 256, 0, stream>>>(x, lnfw, lnfb, hbuf);
    gemm_bt<3, true><<<dim3(16 * (VP2 / 128), 1), 256, 0, stream>>>(hbuf, tokp, nullptr,
                                                       (float*)d_out, nullptr,
                                                       BTOT, VP2, 768, VV, VV);
}